// Round 1
// baseline (2853.859 us; speedup 1.0000x reference)
//
#include <hip/hip_runtime.h>
#include <math.h>

#define B_   16
#define HH   32
#define WW   32
#define NN   1024
#define DIM_ 512
#define D1_  1536
#define NH_  8
#define HD_  192
#define GLU_ 1024

__device__ __forceinline__ float silu_f(float x) {
    return x / (1.0f + __expf(-x));
}

// ---------------- K1: RPE MLP -> coefD[4096][1536] (decay fused) ----------------
__global__ void rpe_coef_kernel(const float* __restrict__ pos_w, const float* __restrict__ pos_b,
                                const float* __restrict__ lw, const float* __restrict__ lb,
                                const float* __restrict__ ow, const float* __restrict__ ob,
                                float* __restrict__ coefD) {
    int a = blockIdx.x;          // 0..4095 = a1*64 + a2
    int a1 = a >> 6, a2 = a & 63;
    float di = (a1 < 32) ? (float)a1 : (float)(a1 - 64);
    float dj = (a2 < 32) ? (float)a2 : (float)(a2 - 64);
    int t = threadIdx.x;         // 0..63, one wave
    __shared__ float yb[64];
    float x = di * pos_w[t] + dj * pos_w[64 + t] + pos_b[t];
    for (int L = 0; L < 3; ++L) {
        float ss = x * x;
        #pragma unroll
        for (int o = 32; o > 0; o >>= 1) ss += __shfl_xor(ss, o, 64);
        float y = x / (sqrtf(ss) * 0.125f + 1e-8f);   // srms, d=64
        y = silu_f(y);
        yb[t] = y;
        __syncthreads();
        float acc = lb[L * 64 + t];
        const float* w = lw + L * 4096 + t;           // lw[L][k][t]
        #pragma unroll 8
        for (int k = 0; k < 64; ++k) acc = fmaf(yb[k], w[k * 64], acc);
        __syncthreads();
        x = acc;
    }
    float ss = x * x;
    #pragma unroll
    for (int o = 32; o > 0; o >>= 1) ss += __shfl_xor(ss, o, 64);
    float y = x / (sqrtf(ss) * 0.125f + 1e-8f);
    y = silu_f(y);
    yb[t] = y;
    __syncthreads();
    // decay = 0.999^(|di|+|dj|)
    float decay = __expf(-0.0010005003335835344f * (fabsf(di) + fabsf(dj)));
    for (int c = t; c < D1_; c += 64) {
        float acc = ob[c];
        #pragma unroll 8
        for (int k = 0; k < 64; ++k) acc = fmaf(yb[k], ow[k * D1_ + c], acc);
        coefD[(size_t)a * D1_ + c] = acc * decay;
    }
}

// ---------------- K2: generic fp32 tiled GEMM, 64x64 tile, 4x4/thread ----------------
// MODE 0: C = silu(A@W1+b1)
// MODE 1: C = A@W1+b1+R
// MODE 2: C = silu(A@W1+b1)*(A@W2+b2)
// MODE 3: C = A@W1+b1
template<int MODE>
__launch_bounds__(256)
__global__ void gemm_kernel(const float* __restrict__ A, const float* __restrict__ W1,
                            const float* __restrict__ b1, const float* __restrict__ W2,
                            const float* __restrict__ b2, const float* __restrict__ R,
                            float* __restrict__ C, int M, int K, int Nn) {
    __shared__ float Ast[16][68];   // A tile transposed [k][m], pad 68 keeps float4 aligned (272B=17*16)
    __shared__ float Bs[16][64];
    __shared__ float Bs2[16][64];
    int t = threadIdx.x;
    int tx = t & 15, ty = t >> 4;
    int n0 = blockIdx.x * 64;
    int m0 = blockIdx.y * 64;
    float acc[4][4] = {};
    float acc2[4][4] = {};
    int lr = t >> 2;            // 0..63  (A tile row)
    int lk = (t & 3) << 2;      // 0,4,8,12 (A tile k quad)
    int bk = t >> 4;            // 0..15 (B tile k)
    int bc = (t & 15) << 2;     // 0..60 (B tile col quad)
    for (int k0 = 0; k0 < K; k0 += 16) {
        float4 av = *reinterpret_cast<const float4*>(&A[(size_t)(m0 + lr) * K + k0 + lk]);
        Ast[lk + 0][lr] = av.x; Ast[lk + 1][lr] = av.y;
        Ast[lk + 2][lr] = av.z; Ast[lk + 3][lr] = av.w;
        float4 bv = *reinterpret_cast<const float4*>(&W1[(size_t)(k0 + bk) * Nn + n0 + bc]);
        *reinterpret_cast<float4*>(&Bs[bk][bc]) = bv;
        if (MODE == 2) {
            float4 bv2 = *reinterpret_cast<const float4*>(&W2[(size_t)(k0 + bk) * Nn + n0 + bc]);
            *reinterpret_cast<float4*>(&Bs2[bk][bc]) = bv2;
        }
        __syncthreads();
        #pragma unroll
        for (int kk = 0; kk < 16; ++kk) {
            float4 a4 = *reinterpret_cast<const float4*>(&Ast[kk][ty << 2]);
            float4 b4 = *reinterpret_cast<const float4*>(&Bs[kk][tx << 2]);
            float aa[4] = {a4.x, a4.y, a4.z, a4.w};
            float bb[4] = {b4.x, b4.y, b4.z, b4.w};
            #pragma unroll
            for (int i = 0; i < 4; ++i)
                #pragma unroll
                for (int j = 0; j < 4; ++j)
                    acc[i][j] = fmaf(aa[i], bb[j], acc[i][j]);
            if (MODE == 2) {
                float4 c4 = *reinterpret_cast<const float4*>(&Bs2[kk][tx << 2]);
                float cc[4] = {c4.x, c4.y, c4.z, c4.w};
                #pragma unroll
                for (int i = 0; i < 4; ++i)
                    #pragma unroll
                    for (int j = 0; j < 4; ++j)
                        acc2[i][j] = fmaf(aa[i], cc[j], acc2[i][j]);
            }
        }
        __syncthreads();
    }
    #pragma unroll
    for (int i = 0; i < 4; ++i) {
        int row = m0 + (ty << 2) + i;
        #pragma unroll
        for (int j = 0; j < 4; ++j) {
            int col = n0 + (tx << 2) + j;
            size_t idx = (size_t)row * Nn + col;
            float vv = acc[i][j] + b1[col];
            if (MODE == 0) {
                C[idx] = silu_f(vv);
            } else if (MODE == 1) {
                C[idx] = vv + R[idx];
            } else if (MODE == 2) {
                float v2 = acc2[i][j] + b2[col];
                C[idx] = silu_f(vv) * v2;
            } else {
                C[idx] = vv;
            }
        }
    }
}

// ---------------- K3: direct block-Toeplitz 2D circular conv, fused u *= mix ----------------
// mix[b,i,j,c] = sum_{i',j'<32} coefD[(i-i')&63][(j-j')&63][c] * v[b,i'*32+j',c]
__launch_bounds__(256)
__global__ void conv_mul_kernel(const float* __restrict__ coefD, const float* __restrict__ v,
                                float* __restrict__ u) {
    int c = blockIdx.x * 256 + threadIdx.x;   // channel 0..1535
    int i = blockIdx.y;                        // output row 0..31
    int b = blockIdx.z;                        // batch 0..15
    float acc[32];
    #pragma unroll
    for (int j = 0; j < 32; ++j) acc[j] = 0.0f;
    const float* vb = v + (size_t)b * NN * D1_ + c;
    for (int i2 = 0; i2 < 32; ++i2) {
        int r = (i - i2) & 63;
        const float* crow = coefD + (size_t)r * 64 * D1_ + c;
        float cr[64];
        #pragma unroll
        for (int dj = 0; dj < 64; ++dj) cr[dj] = crow[(size_t)dj * D1_];
        const float* vrow = vb + (size_t)i2 * 32 * D1_;
        float vv[32];
        #pragma unroll
        for (int j2 = 0; j2 < 32; ++j2) vv[j2] = vrow[(size_t)j2 * D1_];
        #pragma unroll
        for (int j2 = 0; j2 < 32; ++j2) {
            float vj = vv[j2];
            #pragma unroll
            for (int j = 0; j < 32; ++j)
                acc[j] = fmaf(cr[(j - j2) & 63], vj, acc[j]);  // static idx -> regs
        }
    }
    float* ub = u + (size_t)b * NN * D1_ + (size_t)i * 32 * D1_ + c;
    #pragma unroll
    for (int j = 0; j < 32; ++j) ub[(size_t)j * D1_] *= acc[j];
}

// ---------------- K4: out = x2 + srms(m) (row-wise over 512) ----------------
__launch_bounds__(256)
__global__ void final_kernel(const float* __restrict__ x2, const float* __restrict__ m,
                             float* __restrict__ out) {
    int row = blockIdx.x;
    const float* mr = m + (size_t)row * DIM_;
    const float* xr = x2 + (size_t)row * DIM_;
    float* orow = out + (size_t)row * DIM_;
    int t = threadIdx.x;
    float a = mr[t], b2 = mr[t + 256];
    float ss = a * a + b2 * b2;
    #pragma unroll
    for (int o = 32; o > 0; o >>= 1) ss += __shfl_xor(ss, o, 64);
    __shared__ float red[4];
    int wid = t >> 6;
    if ((t & 63) == 0) red[wid] = ss;
    __syncthreads();
    float tot = red[0] + red[1] + red[2] + red[3];
    float inv = 1.0f / (sqrtf(tot) * 0.044194173824159216f + 1e-8f);  // 1/sqrt(512)
    orow[t]       = xr[t]       + a  * inv;
    orow[t + 256] = xr[t + 256] + b2 * inv;
}

extern "C" void kernel_launch(void* const* d_in, const int* in_sizes, int n_in,
                              void* d_out, int out_size, void* d_ws, size_t ws_size,
                              hipStream_t stream) {
    const float* x     = (const float*)d_in[0];
    const float* u_w   = (const float*)d_in[1];
    const float* u_b   = (const float*)d_in[2];
    const float* v_w   = (const float*)d_in[3];
    const float* v_b   = (const float*)d_in[4];
    const float* o_w   = (const float*)d_in[5];
    const float* o_b   = (const float*)d_in[6];
    const float* pos_w = (const float*)d_in[7];
    const float* pos_b = (const float*)d_in[8];
    const float* rpe_lw = (const float*)d_in[9];
    const float* rpe_lb = (const float*)d_in[10];
    const float* rpe_ow = (const float*)d_in[11];
    const float* rpe_ob = (const float*)d_in[12];
    const float* l1_w  = (const float*)d_in[13];
    const float* l1_b  = (const float*)d_in[14];
    const float* l2_w  = (const float*)d_in[15];
    const float* l2_b  = (const float*)d_in[16];
    const float* l3_w  = (const float*)d_in[17];
    const float* l3_b  = (const float*)d_in[18];
    float* out = (float*)d_out;

    // workspace layout (floats):
    float* ws    = (float*)d_ws;
    float* coefD = ws;                    //  6,291,456  (4096 x 1536)
    float* u     = coefD + 6291456;       // 25,165,824  (16384 x 1536)
    float* v     = u + 25165824;          // 25,165,824
    float* x2    = v + 25165824;          //  8,388,608  (16384 x 512)
    float* p     = v;                     // reuse v region after conv (16384 x 1024)
    float* mm    = v + 16777216;          // 8,388,608 (16384 x 512), still inside v region

    const int M = B_ * NN;  // 16384

    // 1) RPE coefficients (with decay)
    rpe_coef_kernel<<<4096, 64, 0, stream>>>(pos_w, pos_b, rpe_lw, rpe_lb, rpe_ow, rpe_ob, coefD);
    // 2) u = silu(x@u_w+u_b), v = silu(x@v_w+v_b)
    gemm_kernel<0><<<dim3(D1_ / 64, M / 64), 256, 0, stream>>>(x, u_w, u_b, nullptr, nullptr, nullptr, u, M, DIM_, D1_);
    gemm_kernel<0><<<dim3(D1_ / 64, M / 64), 256, 0, stream>>>(x, v_w, v_b, nullptr, nullptr, nullptr, v, M, DIM_, D1_);
    // 3) token mixing (direct circular conv), fused u *= mix
    conv_mul_kernel<<<dim3(D1_ / 256, 32, 16), 256, 0, stream>>>(coefD, v, u);
    // 4) x2 = x + u@o_w + o_b
    gemm_kernel<1><<<dim3(DIM_ / 64, M / 64), 256, 0, stream>>>(u, o_w, o_b, nullptr, nullptr, x, x2, M, D1_, DIM_);
    // 5) p = silu(x2@l1+b1)*(x2@l2+b2)
    gemm_kernel<2><<<dim3(GLU_ / 64, M / 64), 256, 0, stream>>>(x2, l1_w, l1_b, l2_w, l2_b, nullptr, p, M, DIM_, GLU_);
    // 6) mm = p@l3+b3
    gemm_kernel<3><<<dim3(DIM_ / 64, M / 64), 256, 0, stream>>>(p, l3_w, l3_b, nullptr, nullptr, nullptr, mm, M, GLU_, DIM_);
    // 7) out = x2 + srms(mm)
    final_kernel<<<M, 256, 0, stream>>>(x2, mm, out);
}

// Round 4
// 1088.515 us; speedup vs baseline: 2.6218x; 2.6218x over previous
//
#include <hip/hip_runtime.h>
#include <math.h>

#define B_   16
#define NN   1024
#define DIM_ 512
#define D1_  1536
#define GLU_ 1024

typedef unsigned short u16;
typedef __attribute__((ext_vector_type(8))) short bf16x8;
typedef __attribute__((ext_vector_type(4))) float f32x4;

__device__ __forceinline__ float silu_f(float x) {
    return x / (1.0f + __expf(-x));
}
__device__ __forceinline__ u16 f2b(float f) {           // RNE fp32 -> bf16
    unsigned u = __float_as_uint(f);
    return (u16)((u + 0x7FFF + ((u >> 16) & 1)) >> 16);
}
__device__ __forceinline__ float b2f(u16 s) {
    return __uint_as_float(((unsigned)s) << 16);
}

// ---------------- prep: fp32 -> bf16 (vectorized) ----------------
__global__ void cvt_kernel(const float* __restrict__ in, u16* __restrict__ out, int n4) {
    int i = blockIdx.x * 256 + threadIdx.x;
    if (i >= n4) return;
    float4 f = reinterpret_cast<const float4*>(in)[i];
    unsigned lo = (unsigned)f2b(f.x) | ((unsigned)f2b(f.y) << 16);
    unsigned hi = (unsigned)f2b(f.z) | ((unsigned)f2b(f.w) << 16);
    reinterpret_cast<uint2*>(out)[i] = make_uint2(lo, hi);
}

// ---------------- prep: transpose K x N fp32 -> N x K bf16 ----------------
__global__ void transpose_cvt_kernel(const float* __restrict__ in, u16* __restrict__ out,
                                     int K, int N) {
    __shared__ float tile[32][33];
    int n0 = blockIdx.x * 32, k0 = blockIdx.y * 32;
    int tx = threadIdx.x, ty = threadIdx.y;            // 32 x 8
    #pragma unroll
    for (int r = 0; r < 32; r += 8)
        tile[ty + r][tx] = in[(size_t)(k0 + ty + r) * N + n0 + tx];
    __syncthreads();
    #pragma unroll
    for (int r = 0; r < 32; r += 8)
        out[(size_t)(n0 + ty + r) * K + k0 + tx] = f2b(tile[tx][ty + r]);
}

__global__ void concat_bias_kernel(const float* __restrict__ a, const float* __restrict__ b,
                                   float* __restrict__ o) {
    int t = blockIdx.x * 256 + threadIdx.x;
    if (t < 1024) o[t] = a[t];
    else if (t < 2048) o[t] = b[t - 1024];
}

// ---------------- K1: RPE MLP -> coefD[4096][1536] bf16 (decay fused) ----------------
__global__ void rpe_coef_kernel(const float* __restrict__ pos_w, const float* __restrict__ pos_b,
                                const float* __restrict__ lw, const float* __restrict__ lb,
                                const float* __restrict__ ow, const float* __restrict__ ob,
                                u16* __restrict__ coefD) {
    int a = blockIdx.x;          // 0..4095 = a1*64 + a2
    int a1 = a >> 6, a2 = a & 63;
    float di = (a1 < 32) ? (float)a1 : (float)(a1 - 64);
    float dj = (a2 < 32) ? (float)a2 : (float)(a2 - 64);
    int t = threadIdx.x;         // 0..63, one wave
    __shared__ float yb[64];
    float x = di * pos_w[t] + dj * pos_w[64 + t] + pos_b[t];
    for (int L = 0; L < 3; ++L) {
        float ss = x * x;
        #pragma unroll
        for (int o = 32; o > 0; o >>= 1) ss += __shfl_xor(ss, o, 64);
        float y = silu_f(x / (sqrtf(ss) * 0.125f + 1e-8f));
        yb[t] = y;
        __syncthreads();
        float acc = lb[L * 64 + t];
        const float* w = lw + L * 4096 + t;
        #pragma unroll 8
        for (int k = 0; k < 64; ++k) acc = fmaf(yb[k], w[k * 64], acc);
        __syncthreads();
        x = acc;
    }
    float ss = x * x;
    #pragma unroll
    for (int o = 32; o > 0; o >>= 1) ss += __shfl_xor(ss, o, 64);
    float y = silu_f(x / (sqrtf(ss) * 0.125f + 1e-8f));
    yb[t] = y;
    __syncthreads();
    float decay = __expf(-0.0010005003335835344f * (fabsf(di) + fabsf(dj)));
    for (int c = t; c < D1_; c += 64) {
        float acc = ob[c];
        #pragma unroll 8
        for (int k = 0; k < 64; ++k) acc = fmaf(yb[k], ow[k * D1_ + c], acc);
        coefD[(size_t)a * D1_ + c] = f2b(acc * decay);
    }
}

// ---------------- K2: bf16 MFMA GEMM, 128x128 tile, BK=64, B^T input ----------------
// EPI 0: C0 = bf16(silu(acc+b))          EPI 1: C0 = fp32(acc+b+R), C1 = bf16(same)
// EPI 2: C0 = bf16(acc+b)                EPI 3: C0 = fp32(acc+b)
template<int EPI>
__launch_bounds__(256, 2)
__global__ void mfma_gemm(const u16* __restrict__ A, const u16* __restrict__ BT,
                          const float* __restrict__ bias, const float* __restrict__ R,
                          void* __restrict__ C0, void* __restrict__ C1,
                          int M, int N, int K) {
    __shared__ __align__(16) u16 Asmem[128 * 64];   // 16KB, [row][8 slots of 16B], XOR-swizzled
    __shared__ __align__(16) u16 Bsmem[128 * 64];
    int tid = threadIdx.x;
    int w = tid >> 6, lane = tid & 63;
    int lr = lane & 15, kg = lane >> 4;
    int wr = w >> 1, wc = w & 1;                     // 2x2 waves, each 64x64
    int m0 = blockIdx.y * 128, n0 = blockIdx.x * 128;
    f32x4 acc[4][4] = {};
    for (int k0 = 0; k0 < K; k0 += 64) {
        // stage A,B tiles: linear LDS dest, pre-swizzled global source (rule 21)
        #pragma unroll
        for (int r = 0; r < 4; ++r) {
            int c4 = (r * 4 + w) * 64 + lane;        // 16B chunk index 0..1023
            int row = c4 >> 3, slot = c4 & 7;
            int sl = slot ^ (row & 7);
            const u16* ga = A + (size_t)(m0 + row) * K + k0 + sl * 8;
            const u16* gb = BT + (size_t)(n0 + row) * K + k0 + sl * 8;
            u16* la = Asmem + (r * 4 + w) * 512;     // wave-uniform base, HW adds lane*16B
            u16* lb = Bsmem + (r * 4 + w) * 512;
            __builtin_amdgcn_global_load_lds((const __attribute__((address_space(1))) void*)ga,
                                             (__attribute__((address_space(3))) void*)la, 16, 0, 0);
            __builtin_amdgcn_global_load_lds((const __attribute__((address_space(1))) void*)gb,
                                             (__attribute__((address_space(3))) void*)lb, 16, 0, 0);
        }
        __syncthreads();                              // drains vmcnt before barrier
        #pragma unroll
        for (int kk = 0; kk < 2; ++kk) {
            bf16x8 af[4], bfr[4];
            #pragma unroll
            for (int m = 0; m < 4; ++m) {
                int row = wr * 64 + m * 16 + lr;
                int sl = (kk * 4 + kg) ^ (row & 7);
                af[m] = *reinterpret_cast<const bf16x8*>(&Asmem[row * 64 + sl * 8]);
            }
            #pragma unroll
            for (int n = 0; n < 4; ++n) {
                int row = wc * 64 + n * 16 + lr;
                int sl = (kk * 4 + kg) ^ (row & 7);
                bfr[n] = *reinterpret_cast<const bf16x8*>(&Bsmem[row * 64 + sl * 8]);
            }
            #pragma unroll
            for (int m = 0; m < 4; ++m)
                #pragma unroll
                for (int n = 0; n < 4; ++n)
                    acc[m][n] = __builtin_amdgcn_mfma_f32_16x16x32_bf16(af[m], bfr[n], acc[m][n], 0, 0, 0);
        }
        __syncthreads();
    }
    // epilogue: C/D layout col=lane&15, row=(lane>>4)*4+q  [m89]
    #pragma unroll
    for (int m = 0; m < 4; ++m) {
        #pragma unroll
        for (int n = 0; n < 4; ++n) {
            #pragma unroll
            for (int q = 0; q < 4; ++q) {
                int row = m0 + wr * 64 + m * 16 + kg * 4 + q;
                int col = n0 + wc * 64 + n * 16 + lr;
                size_t idx = (size_t)row * N + col;
                float vv = acc[m][n][q] + bias[col];
                if (EPI == 0) {
                    ((u16*)C0)[idx] = f2b(silu_f(vv));
                } else if (EPI == 1) {
                    float t2 = vv + R[idx];
                    ((float*)C0)[idx] = t2;
                    ((u16*)C1)[idx] = f2b(t2);
                } else if (EPI == 2) {
                    ((u16*)C0)[idx] = f2b(vv);
                } else {
                    ((float*)C0)[idx] = vv;
                }
            }
        }
    }
}

// ---------------- K3: direct block-Toeplitz 2D circular conv (bf16), fused u *= mix ----------------
__launch_bounds__(256)
__global__ void conv_mul_kernel(const u16* __restrict__ coefD, const u16* __restrict__ v,
                                u16* __restrict__ u) {
    int c = blockIdx.x * 256 + threadIdx.x;   // channel 0..1535
    int i = blockIdx.y;                        // output row 0..31
    int b = blockIdx.z;                        // batch 0..15
    float acc[32];
    #pragma unroll
    for (int j = 0; j < 32; ++j) acc[j] = 0.0f;
    const u16* vb = v + (size_t)b * NN * D1_ + c;
    for (int i2 = 0; i2 < 32; ++i2) {
        int r = (i - i2) & 63;
        const u16* crow = coefD + (size_t)r * 64 * D1_ + c;
        float cr[64];
        #pragma unroll
        for (int dj = 0; dj < 64; ++dj) cr[dj] = b2f(crow[(size_t)dj * D1_]);
        const u16* vrow = vb + (size_t)i2 * 32 * D1_;
        float vv[32];
        #pragma unroll
        for (int j2 = 0; j2 < 32; ++j2) vv[j2] = b2f(vrow[(size_t)j2 * D1_]);
        #pragma unroll
        for (int j2 = 0; j2 < 32; ++j2) {
            float vj = vv[j2];
            #pragma unroll
            for (int j = 0; j < 32; ++j)
                acc[j] = fmaf(cr[(j - j2) & 63], vj, acc[j]);
        }
    }
    u16* ub = u + (size_t)b * NN * D1_ + (size_t)i * 32 * D1_ + c;
    #pragma unroll
    for (int j = 0; j < 32; ++j) ub[(size_t)j * D1_] = f2b(b2f(ub[(size_t)j * D1_]) * acc[j]);
}

// ---------------- K4: p = silu(t[:, :1024]) * t[:, 1024:]  (bf16) ----------------
__global__ void glu_combine_kernel(const u16* __restrict__ t, u16* __restrict__ p) {
    int i = blockIdx.x * 256 + threadIdx.x;   // 4 elems each, 16384*256 total
    int row = i >> 8;
    int c4 = (i & 255) * 4;
    size_t off1 = (size_t)row * 2048 + c4;
    u16 va[4], vb4[4], po[4];
    *reinterpret_cast<uint2*>(va) = *reinterpret_cast<const uint2*>(t + off1);
    *reinterpret_cast<uint2*>(vb4) = *reinterpret_cast<const uint2*>(t + off1 + 1024);
    #pragma unroll
    for (int q = 0; q < 4; ++q) po[q] = f2b(silu_f(b2f(va[q])) * b2f(vb4[q]));
    *reinterpret_cast<uint2*>(p + (size_t)row * 1024 + c4) = *reinterpret_cast<uint2*>(po);
}

// ---------------- K5: out = x2 + srms(mm) ----------------
__launch_bounds__(256)
__global__ void final_kernel(const float* __restrict__ x2, const float* __restrict__ m,
                             float* __restrict__ out) {
    int row = blockIdx.x;
    const float* mr = m + (size_t)row * DIM_;
    const float* xr = x2 + (size_t)row * DIM_;
    float* orow = out + (size_t)row * DIM_;
    int t = threadIdx.x;
    float a = mr[t], b2 = mr[t + 256];
    float ss = a * a + b2 * b2;
    #pragma unroll
    for (int o = 32; o > 0; o >>= 1) ss += __shfl_xor(ss, o, 64);
    __shared__ float red[4];
    int wid = t >> 6;
    if ((t & 63) == 0) red[wid] = ss;
    __syncthreads();
    float tot = red[0] + red[1] + red[2] + red[3];
    float inv = 1.0f / (sqrtf(tot) * 0.044194173824159216f + 1e-8f);
    orow[t]       = xr[t]       + a  * inv;
    orow[t + 256] = xr[t + 256] + b2 * inv;
}

extern "C" void kernel_launch(void* const* d_in, const int* in_sizes, int n_in,
                              void* d_out, int out_size, void* d_ws, size_t ws_size,
                              hipStream_t stream) {
    const float* x     = (const float*)d_in[0];
    const float* u_w   = (const float*)d_in[1];
    const float* u_b   = (const float*)d_in[2];
    const float* v_w   = (const float*)d_in[3];
    const float* v_b   = (const float*)d_in[4];
    const float* o_w   = (const float*)d_in[5];
    const float* o_b   = (const float*)d_in[6];
    const float* pos_w = (const float*)d_in[7];
    const float* pos_b = (const float*)d_in[8];
    const float* rpe_lw = (const float*)d_in[9];
    const float* rpe_lb = (const float*)d_in[10];
    const float* rpe_ow = (const float*)d_in[11];
    const float* rpe_ob = (const float*)d_in[12];
    const float* l1_w  = (const float*)d_in[13];
    const float* l1_b  = (const float*)d_in[14];
    const float* l2_w  = (const float*)d_in[15];
    const float* l2_b  = (const float*)d_in[16];
    const float* l3_w  = (const float*)d_in[17];
    const float* l3_b  = (const float*)d_in[18];
    float* out = (float*)d_out;

    // -------- workspace layout (bf16 elems unless noted) --------
    u16* coefD = (u16*)d_ws;                 //  6,291,456
    u16* xb    = coefD + 6291456;            //  8,388,608
    u16* u     = xb + 8388608;               // 25,165,824
    u16* v     = u + 25165824;               // 25,165,824
    float* x2  = (float*)(v + 25165824);     //  8,388,608 fp32
    u16* x2b   = (u16*)(x2 + 8388608);       //  8,388,608
    u16* uwT   = x2b + 8388608;              //    786,432
    u16* vwT   = uwT + 786432;
    u16* owT   = vwT + 786432;
    u16* gluT  = owT + 786432;               //  1,048,576 (l1T ++ l2T)
    u16* l3T   = gluT + 1048576;             //    524,288
    float* gluB = (float*)(l3T + 524288);    //      2,048 fp32
    // overlays on the dead u/v region:
    u16* tmp   = u;                           // 33,554,432 (GLU pre-activation, after o-proj)
    u16* p     = u + 33554432;                // 16,777,216
    float* mm  = (float*)u;                   //  8,388,608 fp32 (after tmp dead)

    const int M = B_ * NN;  // 16384

    // prep: conversions / transposes (tiny)
    cvt_kernel<<<(M * DIM_ / 4 + 255) / 256, 256, 0, stream>>>(x, xb, M * DIM_ / 4);
    dim3 tb(32, 8);
    transpose_cvt_kernel<<<dim3(D1_ / 32, DIM_ / 32), tb, 0, stream>>>(u_w, uwT, DIM_, D1_);
    transpose_cvt_kernel<<<dim3(D1_ / 32, DIM_ / 32), tb, 0, stream>>>(v_w, vwT, DIM_, D1_);
    transpose_cvt_kernel<<<dim3(DIM_ / 32, D1_ / 32), tb, 0, stream>>>(o_w, owT, D1_, DIM_);
    transpose_cvt_kernel<<<dim3(GLU_ / 32, DIM_ / 32), tb, 0, stream>>>(l1_w, gluT, DIM_, GLU_);
    transpose_cvt_kernel<<<dim3(GLU_ / 32, DIM_ / 32), tb, 0, stream>>>(l2_w, gluT + (size_t)GLU_ * DIM_, DIM_, GLU_);
    transpose_cvt_kernel<<<dim3(DIM_ / 32, GLU_ / 32), tb, 0, stream>>>(l3_w, l3T, GLU_, DIM_);
    concat_bias_kernel<<<8, 256, 0, stream>>>(l1_b, l2_b, gluB);
    rpe_coef_kernel<<<4096, 64, 0, stream>>>(pos_w, pos_b, rpe_lw, rpe_lb, rpe_ow, rpe_ob, coefD);

    // u = silu(x@u_w+b), v = silu(x@v_w+b)   [bf16 out]
    mfma_gemm<0><<<dim3(D1_ / 128, M / 128), 256, 0, stream>>>(xb, uwT, u_b, nullptr, u, nullptr, M, D1_, DIM_);
    mfma_gemm<0><<<dim3(D1_ / 128, M / 128), 256, 0, stream>>>(xb, vwT, v_b, nullptr, v, nullptr, M, D1_, DIM_);
    // token mixing: u *= conv(v, coef)
    conv_mul_kernel<<<dim3(D1_ / 256, 32, B_), 256, 0, stream>>>(coefD, v, u);
    // x2 = x + u@o_w + b   [fp32 + bf16 copy]
    mfma_gemm<1><<<dim3(DIM_ / 128, M / 128), 256, 0, stream>>>(u, owT, o_b, x, x2, x2b, M, DIM_, D1_);
    // tmp = x2b @ [l1|l2] + [b1|b2]   [bf16, N=2048]
    mfma_gemm<2><<<dim3(2 * GLU_ / 128, M / 128), 256, 0, stream>>>(x2b, gluT, gluB, nullptr, tmp, nullptr, M, 2 * GLU_, DIM_);
    // p = silu(tmp1)*tmp2
    glu_combine_kernel<<<M * GLU_ / 4 / 256, 256, 0, stream>>>(tmp, p);
    // mm = p@l3 + b3   [fp32]
    mfma_gemm<3><<<dim3(DIM_ / 128, M / 128), 256, 0, stream>>>(p, l3T, l3_b, nullptr, mm, nullptr, M, DIM_, GLU_);
    // out = x2 + srms(mm)
    final_kernel<<<M, 256, 0, stream>>>(x2, mm, out);
}

// Round 5
// 590.652 us; speedup vs baseline: 4.8317x; 1.8429x over previous
//
#include <hip/hip_runtime.h>
#include <math.h>

#define B_   16
#define NN   1024
#define DIM_ 512
#define D1_  1536
#define GLU_ 1024

typedef unsigned short u16;
typedef __attribute__((ext_vector_type(8))) short bf16x8;
typedef __attribute__((ext_vector_type(4))) float f32x4;

__device__ __forceinline__ float silu_f(float x) {
    return x / (1.0f + __expf(-x));
}
__device__ __forceinline__ u16 f2b(float f) {           // RNE fp32 -> bf16
    unsigned u = __float_as_uint(f);
    return (u16)((u + 0x7FFF + ((u >> 16) & 1)) >> 16);
}
__device__ __forceinline__ float b2f(u16 s) {
    return __uint_as_float(((unsigned)s) << 16);
}

// ---------------- prep: fp32 -> bf16 (vectorized) ----------------
__global__ void cvt_kernel(const float* __restrict__ in, u16* __restrict__ out, int n4) {
    int i = blockIdx.x * 256 + threadIdx.x;
    if (i >= n4) return;
    float4 f = reinterpret_cast<const float4*>(in)[i];
    unsigned lo = (unsigned)f2b(f.x) | ((unsigned)f2b(f.y) << 16);
    unsigned hi = (unsigned)f2b(f.z) | ((unsigned)f2b(f.w) << 16);
    reinterpret_cast<uint2*>(out)[i] = make_uint2(lo, hi);
}

// ---------------- prep: transpose K x N fp32 -> N x K bf16 ----------------
__global__ void transpose_cvt_kernel(const float* __restrict__ in, u16* __restrict__ out,
                                     int K, int N) {
    __shared__ float tile[32][33];
    int n0 = blockIdx.x * 32, k0 = blockIdx.y * 32;
    int tx = threadIdx.x, ty = threadIdx.y;            // 32 x 8
    #pragma unroll
    for (int r = 0; r < 32; r += 8)
        tile[ty + r][tx] = in[(size_t)(k0 + ty + r) * N + n0 + tx];
    __syncthreads();
    #pragma unroll
    for (int r = 0; r < 32; r += 8)
        out[(size_t)(n0 + ty + r) * K + k0 + tx] = f2b(tile[tx][ty + r]);
}

__global__ void concat_bias_kernel(const float* __restrict__ a, const float* __restrict__ b,
                                   float* __restrict__ o) {
    int t = blockIdx.x * 256 + threadIdx.x;
    if (t < 1024) o[t] = a[t];
    else if (t < 2048) o[t] = b[t - 1024];
}

// ---------------- K1: RPE MLP -> coefD[4096][1536] bf16 (decay fused) ----------------
__global__ void rpe_coef_kernel(const float* __restrict__ pos_w, const float* __restrict__ pos_b,
                                const float* __restrict__ lw, const float* __restrict__ lb,
                                const float* __restrict__ ow, const float* __restrict__ ob,
                                u16* __restrict__ coefD) {
    int a = blockIdx.x;          // 0..4095 = di*64 + dj
    int a1 = a >> 6, a2 = a & 63;
    float di = (a1 < 32) ? (float)a1 : (float)(a1 - 64);
    float dj = (a2 < 32) ? (float)a2 : (float)(a2 - 64);
    int t = threadIdx.x;         // 0..63, one wave
    __shared__ float yb[64];
    float x = di * pos_w[t] + dj * pos_w[64 + t] + pos_b[t];
    for (int L = 0; L < 3; ++L) {
        float ss = x * x;
        #pragma unroll
        for (int o = 32; o > 0; o >>= 1) ss += __shfl_xor(ss, o, 64);
        float y = silu_f(x / (sqrtf(ss) * 0.125f + 1e-8f));
        yb[t] = y;
        __syncthreads();
        float acc = lb[L * 64 + t];
        const float* w = lw + L * 4096 + t;
        #pragma unroll 8
        for (int k = 0; k < 64; ++k) acc = fmaf(yb[k], w[k * 64], acc);
        __syncthreads();
        x = acc;
    }
    float ss = x * x;
    #pragma unroll
    for (int o = 32; o > 0; o >>= 1) ss += __shfl_xor(ss, o, 64);
    float y = silu_f(x / (sqrtf(ss) * 0.125f + 1e-8f));
    yb[t] = y;
    __syncthreads();
    float decay = __expf(-0.0010005003335835344f * (fabsf(di) + fabsf(dj)));
    for (int c = t; c < D1_; c += 64) {
        float acc = ob[c];
        #pragma unroll 8
        for (int k = 0; k < 64; ++k) acc = fmaf(yb[k], ow[k * D1_ + c], acc);
        coefD[(size_t)a * D1_ + c] = f2b(acc * decay);
    }
}

// ---------------- K1b: coefD[di*64+dj][c] -> coefTT[c][dj*64+di] ----------------
__global__ void coef_tt_kernel(const u16* __restrict__ coefD, u16* __restrict__ coefTT) {
    int t = threadIdx.x;                 // 256
    int jg = blockIdx.x;                 // 0..15  (dj groups of 4)
    int ct = blockIdx.y;                 // 0..23  (c tiles of 64)
    int c  = ct * 64 + (t & 63);
    int jj = t >> 6;                     // 0..3
    int dj = jg * 4 + jj;
    #pragma unroll
    for (int oi = 0; oi < 8; ++oi) {
        u16 vals[8];
        #pragma unroll
        for (int m2 = 0; m2 < 8; ++m2) {
            int di = oi * 8 + m2;
            vals[m2] = coefD[(size_t)(di * 64 + dj) * D1_ + c];
        }
        *reinterpret_cast<uint4*>(&coefTT[(size_t)c * 4096 + dj * 64 + oi * 8]) =
            *reinterpret_cast<uint4*>(vals);
    }
}

// ---------------- K2: bf16 MFMA GEMM, 128x128 tile, BK=64, B^T input ----------------
// EPI 0: C0 = bf16(silu(acc+b[col]))     EPI 1: C0 = fp32(acc+b[col]+R), C1 = bf16(same)
// EPI 2: C0 = bf16(acc+b[col])           EPI 3: C0 = fp32(acc+b[col])
// EPI 4: C0 = bf16(silu(acc+b[row]))
// PERMB: source BT row n is remapped to (n&~1023)|((n&31)<<5)|((n>>5)&31)
template<int EPI, int PERMB>
__launch_bounds__(256, 2)
__global__ void mfma_gemm(const u16* __restrict__ A, const u16* __restrict__ BT,
                          const float* __restrict__ bias, const float* __restrict__ R,
                          void* __restrict__ C0, void* __restrict__ C1,
                          int M, int N, int K) {
    __shared__ __align__(16) u16 Asmem[128 * 64];   // 16KB, XOR-swizzled 16B slots
    __shared__ __align__(16) u16 Bsmem[128 * 64];
    int tid = threadIdx.x;
    int w = tid >> 6, lane = tid & 63;
    int lr = lane & 15, kg = lane >> 4;
    int wr = w >> 1, wc = w & 1;                     // 2x2 waves, each 64x64
    int m0 = blockIdx.y * 128, n0 = blockIdx.x * 128;
    f32x4 acc[4][4] = {};
    for (int k0 = 0; k0 < K; k0 += 64) {
        #pragma unroll
        for (int r = 0; r < 4; ++r) {
            int c4 = (r * 4 + w) * 64 + lane;        // 16B chunk index 0..1023
            int row = c4 >> 3, slot = c4 & 7;
            int sl = slot ^ (row & 7);
            const u16* ga = A + (size_t)(m0 + row) * K + k0 + sl * 8;
            int grow = n0 + row;
            if (PERMB) grow = (grow & ~1023) | ((grow & 31) << 5) | ((grow >> 5) & 31);
            const u16* gb = BT + (size_t)grow * K + k0 + sl * 8;
            u16* la = Asmem + (r * 4 + w) * 512;
            u16* lb = Bsmem + (r * 4 + w) * 512;
            __builtin_amdgcn_global_load_lds((const __attribute__((address_space(1))) void*)ga,
                                             (__attribute__((address_space(3))) void*)la, 16, 0, 0);
            __builtin_amdgcn_global_load_lds((const __attribute__((address_space(1))) void*)gb,
                                             (__attribute__((address_space(3))) void*)lb, 16, 0, 0);
        }
        __syncthreads();
        #pragma unroll
        for (int kk = 0; kk < 2; ++kk) {
            bf16x8 af[4], bfr[4];
            #pragma unroll
            for (int m = 0; m < 4; ++m) {
                int row = wr * 64 + m * 16 + lr;
                int sl = (kk * 4 + kg) ^ (row & 7);
                af[m] = *reinterpret_cast<const bf16x8*>(&Asmem[row * 64 + sl * 8]);
            }
            #pragma unroll
            for (int n = 0; n < 4; ++n) {
                int row = wc * 64 + n * 16 + lr;
                int sl = (kk * 4 + kg) ^ (row & 7);
                bfr[n] = *reinterpret_cast<const bf16x8*>(&Bsmem[row * 64 + sl * 8]);
            }
            #pragma unroll
            for (int m = 0; m < 4; ++m)
                #pragma unroll
                for (int n = 0; n < 4; ++n)
                    acc[m][n] = __builtin_amdgcn_mfma_f32_16x16x32_bf16(af[m], bfr[n], acc[m][n], 0, 0, 0);
        }
        __syncthreads();
    }
    #pragma unroll
    for (int m = 0; m < 4; ++m) {
        #pragma unroll
        for (int n = 0; n < 4; ++n) {
            #pragma unroll
            for (int q = 0; q < 4; ++q) {
                int row = m0 + wr * 64 + m * 16 + kg * 4 + q;
                int col = n0 + wc * 64 + n * 16 + lr;
                size_t idx = (size_t)row * N + col;
                if (EPI == 0) {
                    float vv = acc[m][n][q] + bias[col];
                    ((u16*)C0)[idx] = f2b(silu_f(vv));
                } else if (EPI == 1) {
                    float t2 = acc[m][n][q] + bias[col] + R[idx];
                    ((float*)C0)[idx] = t2;
                    ((u16*)C1)[idx] = f2b(t2);
                } else if (EPI == 2) {
                    ((u16*)C0)[idx] = f2b(acc[m][n][q] + bias[col]);
                } else if (EPI == 3) {
                    ((float*)C0)[idx] = acc[m][n][q] + bias[col];
                } else {
                    float vv = acc[m][n][q] + bias[row];
                    ((u16*)C0)[idx] = f2b(silu_f(vv));
                }
            }
        }
    }
}

// ---------------- K3: per-channel block-Toeplitz mixing via MFMA ----------------
// Per channel c: mix[b][p] = sum_{p'} T[p][p'] v[b][p'],
//   T[p][p'] = d2[(i-i')&63][(j-j')&63], p=i*32+j, p'=i'*32+j'.
// K-order k = j'*32+i'. A-frag = vlds[b][k] (XOR-swizzled 16B chunks).
// B-frag from pre-rotated ring tables gt[wv][w][m] (w=(j-j')&63, one aligned b128).
__launch_bounds__(512, 1)
__global__ void conv_mfma_kernel(const u16* __restrict__ coefTT, const u16* __restrict__ vT2,
                                 u16* __restrict__ mixT) {
    __shared__ bf16x8 vlds8[2048];      // 32 KB: [b 16][chunk 128], chunk ^= (b&7)
    __shared__ bf16x8 gt8[4608];        // 73.7 KB: [wv 8][w 64][9 chunks] (72 elems/row)
    __shared__ u16 d2l[4096];           // 8 KB: coefTT[c] = [dj*64 + di]
    int c = blockIdx.x;
    int t = threadIdx.x;
    int wv = t >> 6, lane = t & 63;
    int lr = lane & 15, kg = lane >> 4;

    // stage vlds: 2048 linear 16B chunks, pre-swizzled global source (rule 21)
    u16* vldsp = (u16*)vlds8;
    #pragma unroll
    for (int pass = 0; pass < 4; ++pass) {
        int L = pass * 512 + t;                  // dest chunk (linear in lane)
        int b = L >> 7, k8s = L & 127;
        int k8 = k8s ^ (b & 7);
        const u16* src = vT2 + (size_t)c * 16384 + b * 1024 + k8 * 8;
        u16* dst = vldsp + (size_t)(pass * 512 + wv * 64) * 8;   // wave-uniform base
        __builtin_amdgcn_global_load_lds((const __attribute__((address_space(1))) void*)src,
                                         (__attribute__((address_space(3))) void*)dst, 16, 0, 0);
    }
    {   // stage d2l: 512 chunks
        const u16* src = coefTT + (size_t)c * 4096 + t * 8;
        u16* dst = d2l + wv * 512;
        __builtin_amdgcn_global_load_lds((const __attribute__((address_space(1))) void*)src,
                                         (__attribute__((address_space(3))) void*)dst, 16, 0, 0);
    }
    __syncthreads();
    // build rotated ring tables: gt[wvv][w][m] = d2[( -(m + o) )&63][w], o = (-wvv)&7
    u16* gtp = (u16*)gt8;
    for (int e = t; e < 32768; e += 512) {
        int m = e & 63, w = (e >> 6) & 63, wvv = e >> 12;
        int o = (8 - wvv) & 7;
        int q = (64 - ((m + o) & 63)) & 63;      // (-(m+o)) & 63
        gtp[(wvv * 64 + w) * 72 + m] = d2l[w * 64 + q];
    }
    __syncthreads();

    // K-loop: 32 steps (j'), 8 fragments per wave per step (4 nt x 2 j-half)
    f32x4 acc[4][2] = {};
    const bf16x8* gtw = gt8 + wv * 576;          // this wave's rotated table
    int mbc[4];                                   // aligned chunk index per nt (lane's kg)
    #pragma unroll
    for (int nt = 0; nt < 4; ++nt)
        mbc[nt] = (((kg * 8 - (nt * 8 + wv)) & 63) & ~7) >> 3;
    int lrs = lr & 7;
    for (int jp = 0; jp < 32; ++jp) {
        bf16x8 af = vlds8[lr * 128 + ((jp * 4 + kg) ^ lrs)];
        int w0 = (lr - jp) & 63;
        int w1 = (w0 + 16) & 63;
        #pragma unroll
        for (int nt = 0; nt < 4; ++nt) {
            bf16x8 b0 = gtw[w0 * 9 + mbc[nt]];
            acc[nt][0] = __builtin_amdgcn_mfma_f32_16x16x32_bf16(af, b0, acc[nt][0], 0, 0, 0);
            bf16x8 b1 = gtw[w1 * 9 + mbc[nt]];
            acc[nt][1] = __builtin_amdgcn_mfma_f32_16x16x32_bf16(af, b1, acc[nt][1], 0, 0, 0);
        }
    }
    // store: C/D layout col=lane&15 (=p low), row=kg*4+q (=b)
    size_t base = (size_t)c * 16384 + (size_t)(kg * 4) * 1024 + wv * 32 + lr;
    #pragma unroll
    for (int nt = 0; nt < 4; ++nt)
        #pragma unroll
        for (int h = 0; h < 2; ++h) {
            size_t bb = base + nt * 256 + h * 16;   // i = nt*8+wv -> p += nt*8*32
            #pragma unroll
            for (int q = 0; q < 4; ++q)
                mixT[bb + (size_t)q * 1024] = f2b(acc[nt][h][q]);
        }
}

// ---------------- K4: u[r][c] *= mixT[c][r]  (all coalesced, no LDS) ----------------
__launch_bounds__(256)
__global__ void mult_kernel(const u16* __restrict__ mixT, u16* __restrict__ u) {
    int r = blockIdx.x * 256 + threadIdx.x;      // 0..16383
    int c0 = blockIdx.y * 64;
    #pragma unroll
    for (int oc = 0; oc < 8; ++oc) {
        int cb = c0 + oc * 8;
        float mv[8];
        #pragma unroll
        for (int m2 = 0; m2 < 8; ++m2)
            mv[m2] = b2f(mixT[(size_t)(cb + m2) * 16384 + r]);
        u16 uv[8];
        *reinterpret_cast<uint4*>(uv) = *reinterpret_cast<const uint4*>(&u[(size_t)r * D1_ + cb]);
        #pragma unroll
        for (int m2 = 0; m2 < 8; ++m2) uv[m2] = f2b(b2f(uv[m2]) * mv[m2]);
        *reinterpret_cast<uint4*>(&u[(size_t)r * D1_ + cb]) = *reinterpret_cast<uint4*>(uv);
    }
}

// ---------------- K5: p = silu(t[:, :1024]) * t[:, 1024:]  (bf16) ----------------
__global__ void glu_combine_kernel(const u16* __restrict__ t, u16* __restrict__ p) {
    int i = blockIdx.x * 256 + threadIdx.x;
    int row = i >> 8;
    int c4 = (i & 255) * 4;
    size_t off1 = (size_t)row * 2048 + c4;
    u16 va[4], vb4[4], po[4];
    *reinterpret_cast<uint2*>(va) = *reinterpret_cast<const uint2*>(t + off1);
    *reinterpret_cast<uint2*>(vb4) = *reinterpret_cast<const uint2*>(t + off1 + 1024);
    #pragma unroll
    for (int q = 0; q < 4; ++q) po[q] = f2b(silu_f(b2f(va[q])) * b2f(vb4[q]));
    *reinterpret_cast<uint2*>(p + (size_t)row * 1024 + c4) = *reinterpret_cast<uint2*>(po);
}

// ---------------- K6: out = x2 + srms(mm) ----------------
__launch_bounds__(256)
__global__ void final_kernel(const float* __restrict__ x2, const float* __restrict__ m,
                             float* __restrict__ out) {
    int row = blockIdx.x;
    const float* mr = m + (size_t)row * DIM_;
    const float* xr = x2 + (size_t)row * DIM_;
    float* orow = out + (size_t)row * DIM_;
    int t = threadIdx.x;
    float a = mr[t], b2 = mr[t + 256];
    float ss = a * a + b2 * b2;
    #pragma unroll
    for (int o = 32; o > 0; o >>= 1) ss += __shfl_xor(ss, o, 64);
    __shared__ float red[4];
    int wid = t >> 6;
    if ((t & 63) == 0) red[wid] = ss;
    __syncthreads();
    float tot = red[0] + red[1] + red[2] + red[3];
    float inv = 1.0f / (sqrtf(tot) * 0.044194173824159216f + 1e-8f);
    orow[t]       = xr[t]       + a  * inv;
    orow[t + 256] = xr[t + 256] + b2 * inv;
}

extern "C" void kernel_launch(void* const* d_in, const int* in_sizes, int n_in,
                              void* d_out, int out_size, void* d_ws, size_t ws_size,
                              hipStream_t stream) {
    const float* x     = (const float*)d_in[0];
    const float* u_w   = (const float*)d_in[1];
    const float* u_b   = (const float*)d_in[2];
    const float* v_w   = (const float*)d_in[3];
    const float* v_b   = (const float*)d_in[4];
    const float* o_w   = (const float*)d_in[5];
    const float* o_b   = (const float*)d_in[6];
    const float* pos_w = (const float*)d_in[7];
    const float* pos_b = (const float*)d_in[8];
    const float* rpe_lw = (const float*)d_in[9];
    const float* rpe_lb = (const float*)d_in[10];
    const float* rpe_ow = (const float*)d_in[11];
    const float* rpe_ob = (const float*)d_in[12];
    const float* l1_w  = (const float*)d_in[13];
    const float* l1_b  = (const float*)d_in[14];
    const float* l2_w  = (const float*)d_in[15];
    const float* l2_b  = (const float*)d_in[16];
    const float* l3_w  = (const float*)d_in[17];
    const float* l3_b  = (const float*)d_in[18];
    float* out = (float*)d_out;

    // -------- workspace layout (u16 units unless noted) --------
    u16* coefD  = (u16*)d_ws;                  //  6,291,456
    u16* coefTT = coefD + 6291456;             //  6,291,456
    u16* xb     = coefTT + 6291456;            //  8,388,608
    u16* u      = xb + 8388608;                // 25,165,824
    u16* vT2    = u + 25165824;                // 25,165,824  [c][b*1024 + k], k=j'*32+i'
    u16* mixT   = vT2 + 25165824;              // 25,165,824  [c][r]
    float* x2   = (float*)(mixT + 25165824);   //  8,388,608 fp32
    u16* x2b    = (u16*)(x2 + 8388608);        //  8,388,608
    u16* uwT    = x2b + 8388608;               //    786,432
    u16* vwT    = uwT + 786432;
    u16* owT    = vwT + 786432;
    u16* gluT   = owT + 786432;                //  1,048,576 (l1T ++ l2T)
    u16* l3T    = gluT + 1048576;              //    524,288
    float* gluB = (float*)(l3T + 524288);      //      2,048 fp32
    // overlays:
    u16* tmp    = vT2;                          // 33,554,432 (GLU pre-act; vT2+mixT dead)
    u16* p      = u;                            // 16,777,216 (u dead after o-proj)
    float* mm   = (float*)vT2;                  //  8,388,608 fp32 (tmp dead after combine)

    const int M = B_ * NN;  // 16384

    // prep
    cvt_kernel<<<(M * DIM_ / 4 + 255) / 256, 256, 0, stream>>>(x, xb, M * DIM_ / 4);
    dim3 tb(32, 8);
    transpose_cvt_kernel<<<dim3(D1_ / 32, DIM_ / 32), tb, 0, stream>>>(u_w, uwT, DIM_, D1_);
    transpose_cvt_kernel<<<dim3(D1_ / 32, DIM_ / 32), tb, 0, stream>>>(v_w, vwT, DIM_, D1_);
    transpose_cvt_kernel<<<dim3(DIM_ / 32, D1_ / 32), tb, 0, stream>>>(o_w, owT, D1_, DIM_);
    transpose_cvt_kernel<<<dim3(GLU_ / 32, DIM_ / 32), tb, 0, stream>>>(l1_w, gluT, DIM_, GLU_);
    transpose_cvt_kernel<<<dim3(GLU_ / 32, DIM_ / 32), tb, 0, stream>>>(l2_w, gluT + (size_t)GLU_ * DIM_, DIM_, GLU_);
    transpose_cvt_kernel<<<dim3(DIM_ / 32, GLU_ / 32), tb, 0, stream>>>(l3_w, l3T, GLU_, DIM_);
    concat_bias_kernel<<<8, 256, 0, stream>>>(l1_b, l2_b, gluB);
    rpe_coef_kernel<<<4096, 64, 0, stream>>>(pos_w, pos_b, rpe_lw, rpe_lb, rpe_ow, rpe_ob, coefD);
    coef_tt_kernel<<<dim3(16, 24), 256, 0, stream>>>(coefD, coefTT);

    // u = silu(x@u_w+b)  [16384 x 1536 bf16]
    mfma_gemm<0, 0><<<dim3(D1_ / 128, M / 128), 256, 0, stream>>>(xb, uwT, u_b, nullptr, u, nullptr, M, D1_, DIM_);
    // vT2 = silu(v_w^T @ x^T) with position-permuted cols  [1536 x 16384 bf16]
    mfma_gemm<4, 1><<<dim3(M / 128, D1_ / 128), 256, 0, stream>>>(vwT, xb, v_b, nullptr, vT2, nullptr, D1_, M, DIM_);
    // token mixing on matrix cores: mixT[c][r]
    conv_mfma_kernel<<<1536, 512, 0, stream>>>(coefTT, vT2, mixT);
    // u *= mix
    mult_kernel<<<dim3(M / 256, D1_ / 64), 256, 0, stream>>>(mixT, u);
    // x2 = x + u@o_w + b   [fp32 + bf16 copy]
    mfma_gemm<1, 0><<<dim3(DIM_ / 128, M / 128), 256, 0, stream>>>(u, owT, o_b, x, x2, x2b, M, DIM_, D1_);
    // tmp = x2b @ [l1|l2] + [b1|b2]   [bf16, N=2048]
    mfma_gemm<2, 0><<<dim3(2 * GLU_ / 128, M / 128), 256, 0, stream>>>(x2b, gluT, gluB, nullptr, tmp, nullptr, M, 2 * GLU_, DIM_);
    // p = silu(tmp1)*tmp2
    glu_combine_kernel<<<M * GLU_ / 4 / 256, 256, 0, stream>>>(tmp, p);
    // mm = p@l3 + b3   [fp32]
    mfma_gemm<3, 0><<<dim3(DIM_ / 128, M / 128), 256, 0, stream>>>(p, l3T, l3_b, nullptr, mm, nullptr, M, DIM_, GLU_);
    // out = x2 + srms(mm)
    final_kernel<<<M, 256, 0, stream>>>(x2, mm, out);
}